// Round 1
// baseline (155967.395 us; speedup 1.0000x reference)
//
#include <hip/hip_runtime.h>

typedef unsigned int u32;

#define NN 20000
#define EE 320000
#define DH 128
#define DIN 64
#define TSTEPS 20
#define LNEPS 1e-5f

// ---------- helpers ----------
__device__ __forceinline__ u32 f2bf(float f) {
    u32 x = __float_as_uint(f);
    return (x + 0x7fffu + ((x >> 16) & 1u)) >> 16;   // RNE to bf16 bits
}
__device__ __forceinline__ float bflo(u32 p) { return __uint_as_float(p << 16); }
__device__ __forceinline__ float bfhi(u32 p) { return __uint_as_float(p & 0xffff0000u); }
__device__ __forceinline__ u32 packbf(float a, float b) { return f2bf(a) | (f2bf(b) << 16); }
__device__ __forceinline__ float wredsum(float v) {
#pragma unroll
    for (int m = 32; m >= 1; m >>= 1) v += __shfl_xor(v, m, 64);
    return v;
}
__device__ __forceinline__ float sigm(float x) { return 1.f / (1.f + __expf(-x)); }

// ---------- setup kernels ----------
__global__ void k_init(int* deg, float* oacc) {
    int i = blockIdx.x * blockDim.x + threadIdx.x;
    if (i < NN) deg[i] = 0;
    if (i < DH) oacc[i] = 0.f;
}

__global__ void k_scalars(const float* meth, const float* hist, const float* logd,
                          const float* resw, float* sc) {
    // single thread: tiny
    float msum = 0.f;
    for (int j = 0; j < DH; j++) msum += sigm(meth[j]);
    float msil = msum * (1.f / DH);
    float h0 = sigm(hist[0]), h1 = sigm(hist[1]), h2 = sigm(hist[2]), h3 = sigm(hist[3]);
    float act = 0.5f * (h0 + h2), rep = 0.5f * (h1 + h3);
    float access = fminf(fmaxf(act - rep + 0.5f, 0.f), 1.f);
    sc[0] = access * (1.f - msil);          // epigenetic scale
    float depth = fminf(fmaxf(__expf(logd[0]), 0.1f), 3.f);
    sc[1] = depth / (float)(TSTEPS - 1);    // dt
    sc[2] = resw[0];
}

__global__ void k_deg(const int* col, int* deg) {
    int e = blockIdx.x * blockDim.x + threadIdx.x;
    if (e < EE) atomicAdd(&deg[col[e]], 1);
}

__global__ __launch_bounds__(1024) void k_scan(const int* deg, int* offs, int* cursor, float* dis) {
    __shared__ int part[1024];
    const int CH = (NN + 1023) / 1024;  // 20
    int t = threadIdx.x;
    int base = t * CH;
    int s = 0;
    for (int k = 0; k < CH; k++) { int i = base + k; if (i < NN) s += deg[i]; }
    part[t] = s;
    __syncthreads();
    for (int off = 1; off < 1024; off <<= 1) {
        int v = part[t];
        int add = (t >= off) ? part[t - off] : 0;
        __syncthreads();
        part[t] = v + add;
        __syncthreads();
    }
    int run = part[t] - s;  // exclusive prefix
    for (int k = 0; k < CH; k++) {
        int i = base + k;
        if (i < NN) {
            offs[i] = run; cursor[i] = run;
            int d = deg[i];
            run += d;
            dis[i] = (d > 0) ? rsqrtf((float)d) : 0.f;
        }
    }
    if (t == 1023) offs[NN] = run;  // == EE
}

__global__ void k_scatter(const int* row, const int* col, int* cursor, const float* dis,
                          int* esrc, float* enrm) {
    int e = blockIdx.x * blockDim.x + threadIdx.x;
    if (e < EE) {
        int c = col[e], r = row[e];
        int pos = atomicAdd(&cursor[c], 1);
        esrc[pos] = r;
        enrm[pos] = dis[r] * dis[c];
    }
}

// pack weights to bf16 pairs: pk[k2][j] = (W[2k2][j], W[2k2+1][j])
__global__ void k_convw(const float* gcnw, const float* gatew, const float* Wo,
                        u32* wpk, u32* gwpk, u32* wopk) {
    int i = blockIdx.x * blockDim.x + threadIdx.x;
    if (i < 3 * 64 * DH) {
        int l = i / (64 * DH), rem = i % (64 * DH);
        int k2 = rem / DH, j = rem % DH;
        const float* W = gcnw + l * DH * DH;
        wpk[i] = packbf(W[(2 * k2) * DH + j], W[(2 * k2 + 1) * DH + j]);
    }
    if (i < 128 * DH) {   // gate_w is 256 x 128 -> 128 packed rows
        int k2 = i / DH, j = i % DH;
        gwpk[i] = packbf(gatew[(2 * k2) * DH + j], gatew[(2 * k2 + 1) * DH + j]);
    }
    if (i < 64 * DH) {
        int k2 = i / DH, j = i % DH;
        wopk[i] = packbf(Wo[(2 * k2) * DH + j], Wo[(2 * k2 + 1) * DH + j]);
    }
}

// ---------- input projection: y = bf16(relu(LN(x@Wi+bi))*scale), hh = fp32 same ----------
__global__ __launch_bounds__(1024) void k_inproj(const float* x, const float* Wi, const float* bi,
                                                 const float* g, const float* b, const float* sc,
                                                 u32* y, float* hh) {
    __shared__ float Wl[DIN * DH];  // 32 KB fp32
    for (int i = threadIdx.x; i < DIN * DH; i += 1024) Wl[i] = Wi[i];
    __syncthreads();
    int wv = threadIdx.x >> 6, t = threadIdx.x & 63;
    int n = blockIdx.x * 16 + wv;
    if (n >= NN) return;
    float xv = x[n * DIN + t];  // lane t holds x[t]
    float2 bb = *(const float2*)&bi[2 * t];
    float y0 = bb.x, y1 = bb.y;
#pragma unroll
    for (int k = 0; k < DIN; k++) {
        float a = __shfl(xv, k, 64);
        float2 w = *(const float2*)&Wl[k * DH + 2 * t];
        y0 += a * w.x; y1 += a * w.y;
    }
    float mu = wredsum(y0 + y1) * (1.f / DH);
    float d0 = y0 - mu, d1 = y1 - mu;
    float var = wredsum(d0 * d0 + d1 * d1) * (1.f / DH);
    float r = rsqrtf(var + LNEPS);
    float2 gg = *(const float2*)&g[2 * t], lb = *(const float2*)&b[2 * t];
    float scale = sc[0];
    float v0 = fmaxf(d0 * r * gg.x + lb.x, 0.f) * scale;
    float v1 = fmaxf(d1 * r * gg.y + lb.y, 0.f) * scale;
    y[n * 64 + t] = packbf(v0, v1);
    *(float2*)&hh[n * DH + 2 * t] = make_float2(v0, v1);
}

// ---------- gather + matmul + LN: dst = bf16(LN((A@src)@W + bias)) ----------
__global__ __launch_bounds__(1024) void k_aggmm(const u32* __restrict__ src, u32* __restrict__ dst,
                                                const u32* __restrict__ wpk, const float* bias,
                                                const float* lng, const float* lnb,
                                                const int* __restrict__ offs,
                                                const int* __restrict__ esrc,
                                                const float* __restrict__ enrm) {
    __shared__ u32 Wl[64 * DH];  // 32 KB packed bf16
    for (int i = threadIdx.x; i < 64 * DH; i += 1024) Wl[i] = wpk[i];
    __syncthreads();
    int wv = threadIdx.x >> 6, t = threadIdx.x & 63;
    int n = blockIdx.x * 16 + wv;
    if (n >= NN) return;
    // gather: G[2t], G[2t+1]
    float a0 = 0.f, a1 = 0.f;
    int e0 = offs[n], e1 = offs[n + 1];
    for (int e = e0; e < e1; e++) {
        int s = esrc[e];
        float w = enrm[e];
        u32 p = src[s * 64 + t];
        a0 += w * bflo(p); a1 += w * bfhi(p);
    }
    // row @ W
    float2 bb = *(const float2*)&bias[2 * t];
    float y0 = bb.x, y1 = bb.y;
#pragma unroll
    for (int k2 = 0; k2 < 64; k2++) {
        float g0 = __shfl(a0, k2, 64), g1 = __shfl(a1, k2, 64);
        uint2 w = *(const uint2*)&Wl[k2 * DH + 2 * t];
        y0 += g0 * bflo(w.x) + g1 * bfhi(w.x);
        y1 += g0 * bflo(w.y) + g1 * bfhi(w.y);
    }
    // LayerNorm
    float mu = wredsum(y0 + y1) * (1.f / DH);
    float d0 = y0 - mu, d1 = y1 - mu;
    float var = wredsum(d0 * d0 + d1 * d1) * (1.f / DH);
    float r = rsqrtf(var + LNEPS);
    float2 gg = *(const float2*)&lng[2 * t], lb = *(const float2*)&lnb[2 * t];
    dst[n * 64 + t] = packbf(d0 * r * gg.x + lb.x, d1 * r * gg.y + lb.y);
}

// ---------- gate (+ optional tanh/residual/RK4 epilogue) ----------
template <bool LAST>
__global__ __launch_bounds__(1024) void k_gate(const u32* __restrict__ hc, const u32* __restrict__ hn,
                                               const u32* __restrict__ gwpk, const float* gateb,
                                               u32* hcout, u32* ybuf, float* hh, float* acc,
                                               const float* sc, int rkj) {
    __shared__ u32 Gl[128 * DH];  // 64 KB packed bf16 (256x128 gate_w)
    for (int i = threadIdx.x; i < 128 * DH; i += 1024) Gl[i] = gwpk[i];
    __syncthreads();
    int wv = threadIdx.x >> 6, t = threadIdx.x & 63;
    int n = blockIdx.x * 16 + wv;
    if (n >= NN) return;
    u32 hp = hc[n * 64 + t], np = hn[n * 64 + t];
    float h0 = bflo(hp), h1 = bfhi(hp), n0 = bflo(np), n1 = bfhi(np);
    float2 gb = *(const float2*)&gateb[2 * t];
    float y0 = gb.x, y1 = gb.y;
#pragma unroll
    for (int k2 = 0; k2 < 64; k2++) {  // concat first half: hc
        float a0 = __shfl(h0, k2, 64), a1 = __shfl(h1, k2, 64);
        uint2 w = *(const uint2*)&Gl[k2 * DH + 2 * t];
        y0 += a0 * bflo(w.x) + a1 * bfhi(w.x);
        y1 += a0 * bflo(w.y) + a1 * bfhi(w.y);
    }
#pragma unroll
    for (int k2 = 0; k2 < 64; k2++) {  // second half: hn
        float a0 = __shfl(n0, k2, 64), a1 = __shfl(n1, k2, 64);
        uint2 w = *(const uint2*)&Gl[(64 + k2) * DH + 2 * t];
        y0 += a0 * bflo(w.x) + a1 * bfhi(w.x);
        y1 += a0 * bflo(w.y) + a1 * bfhi(w.y);
    }
    float g0 = sigm(y0), g1 = sigm(y1);
    float o0 = g0 * n0 + (1.f - g0) * h0;
    float o1 = g1 * n1 + (1.f - g1) * h1;
    if (!LAST) {
        hcout[n * 64 + t] = packbf(o0, o1);
    } else {
        // tanh (safe form)
        float z0 = fminf(fmaxf(o0, -15.f), 15.f), z1 = fminf(fmaxf(o1, -15.f), 15.f);
        float e0 = __expf(2.f * z0), e1 = __expf(2.f * z1);
        float t0 = (e0 - 1.f) / (e0 + 1.f), t1 = (e1 - 1.f) / (e1 + 1.f);
        u32 yp = ybuf[n * 64 + t];            // f's input (for residual)
        float dt = sc[1], rw = sc[2];
        float k0 = t0 + rw * bflo(yp), k1 = t1 + rw * bfhi(yp);
        float wj = dt * (1.f / 6.f) * ((rkj == 1 || rkj == 2) ? 2.f : 1.f);
        float2 av;
        if (rkj == 0) { av.x = wj * k0; av.y = wj * k1; }
        else { av = *(float2*)&acc[n * DH + 2 * t]; av.x += wj * k0; av.y += wj * k1; }
        *(float2*)&acc[n * DH + 2 * t] = av;
        float2 hv = *(const float2*)&hh[n * DH + 2 * t];
        if (rkj < 3) {
            float c = (rkj == 2) ? dt : 0.5f * dt;
            ybuf[n * 64 + t] = packbf(hv.x + c * k0, hv.y + c * k1);
        } else {
            float f0 = hv.x + av.x, f1 = hv.y + av.y;
            *(float2*)&hh[n * DH + 2 * t] = make_float2(f0, f1);
            ybuf[n * 64 + t] = packbf(f0, f1);
        }
    }
}

// ---------- output projection + LN + global mean ----------
__global__ __launch_bounds__(1024) void k_outproj(const float* __restrict__ hh, const u32* wopk,
                                                  const float* bo, const float* g, const float* b,
                                                  float* oacc) {
    __shared__ u32 Wl[64 * DH];  // 32 KB
    __shared__ float red[DH];
    for (int i = threadIdx.x; i < 64 * DH; i += 1024) Wl[i] = wopk[i];
    if (threadIdx.x < DH) red[threadIdx.x] = 0.f;
    __syncthreads();
    int wv = threadIdx.x >> 6, t = threadIdx.x & 63;
    int n = blockIdx.x * 16 + wv;
    if (n < NN) {
        float2 hv = *(const float2*)&hh[n * DH + 2 * t];
        float h0 = hv.x, h1 = hv.y;
        float2 bb = *(const float2*)&bo[2 * t];
        float y0 = bb.x, y1 = bb.y;
#pragma unroll
        for (int k2 = 0; k2 < 64; k2++) {
            float a0 = __shfl(h0, k2, 64), a1 = __shfl(h1, k2, 64);
            uint2 w = *(const uint2*)&Wl[k2 * DH + 2 * t];
            y0 += a0 * bflo(w.x) + a1 * bfhi(w.x);
            y1 += a0 * bflo(w.y) + a1 * bfhi(w.y);
        }
        float mu = wredsum(y0 + y1) * (1.f / DH);
        float d0 = y0 - mu, d1 = y1 - mu;
        float var = wredsum(d0 * d0 + d1 * d1) * (1.f / DH);
        float r = rsqrtf(var + LNEPS);
        float2 gg = *(const float2*)&g[2 * t], lb = *(const float2*)&b[2 * t];
        atomicAdd(&red[2 * t], d0 * r * gg.x + lb.x);
        atomicAdd(&red[2 * t + 1], d1 * r * gg.y + lb.y);
    }
    __syncthreads();
    if (threadIdx.x < DH) atomicAdd(&oacc[threadIdx.x], red[threadIdx.x]);
}

__global__ void k_final(const float* oacc, float* out) {
    int t = threadIdx.x;
    if (t < DH) out[t] = oacc[t] * (1.f / (float)NN);
}

// ---------- host ----------
extern "C" void kernel_launch(void* const* d_in, const int* in_sizes, int n_in,
                              void* d_out, int out_size, void* d_ws, size_t ws_size,
                              hipStream_t stream) {
    const float* x     = (const float*)d_in[0];
    const int*   ei    = (const int*)d_in[1];
    const float* Wi    = (const float*)d_in[2];
    const float* bi    = (const float*)d_in[3];
    const float* ling  = (const float*)d_in[4];
    const float* linb  = (const float*)d_in[5];
    const float* meth  = (const float*)d_in[6];
    const float* hist  = (const float*)d_in[7];
    const float* gcnw  = (const float*)d_in[8];
    const float* gcnb  = (const float*)d_in[9];
    const float* lng   = (const float*)d_in[10];
    const float* lnb   = (const float*)d_in[11];
    const float* gatew = (const float*)d_in[12];
    const float* gateb = (const float*)d_in[13];
    const float* resw  = (const float*)d_in[14];
    const float* logd  = (const float*)d_in[15];
    const float* Wo    = (const float*)d_in[16];
    const float* bo    = (const float*)d_in[17];
    const float* loutg = (const float*)d_in[18];
    const float* loutb = (const float*)d_in[19];

    char* wsb = (char*)d_ws;
    size_t off = 0;
    auto alloc = [&](size_t bytes) -> void* {
        void* p = wsb + off;
        off += (bytes + 255) & ~(size_t)255;
        return p;
    };
    float* sc     = (float*)alloc(32);
    int*   deg    = (int*)alloc(NN * 4);
    int*   offs   = (int*)alloc((NN + 1) * 4);
    int*   cursor = (int*)alloc(NN * 4);
    float* dis    = (float*)alloc(NN * 4);
    int*   esrc   = (int*)alloc(EE * 4);
    float* enrm   = (float*)alloc(EE * 4);
    u32*   wpk    = (u32*)alloc(3 * 64 * DH * 4);
    u32*   gwpk   = (u32*)alloc(128 * DH * 4);
    u32*   wopk   = (u32*)alloc(64 * DH * 4);
    u32*   y      = (u32*)alloc((size_t)NN * 64 * 4);
    u32*   hc     = (u32*)alloc((size_t)NN * 64 * 4);
    u32*   hn     = (u32*)alloc((size_t)NN * 64 * 4);
    float* hh     = (float*)alloc((size_t)NN * DH * 4);
    float* acc    = (float*)alloc((size_t)NN * DH * 4);
    float* oacc   = (float*)alloc(DH * 4);

    const int* row = ei;
    const int* col = ei + EE;

    k_init<<<(NN + 255) / 256, 256, 0, stream>>>(deg, oacc);
    k_scalars<<<1, 1, 0, stream>>>(meth, hist, logd, resw, sc);
    k_deg<<<(EE + 255) / 256, 256, 0, stream>>>(col, deg);
    k_scan<<<1, 1024, 0, stream>>>(deg, offs, cursor, dis);
    k_scatter<<<(EE + 255) / 256, 256, 0, stream>>>(row, col, cursor, dis, esrc, enrm);
    k_convw<<<(3 * 64 * DH + 255) / 256, 256, 0, stream>>>(gcnw, gatew, Wo, wpk, gwpk, wopk);

    const int GB = (NN + 15) / 16;  // 16 nodes (waves) per 1024-thread block
    k_inproj<<<GB, 1024, 0, stream>>>(x, Wi, bi, ling, linb, sc, y, hh);

    for (int s = 0; s < TSTEPS - 1; s++) {
        for (int j = 0; j < 4; j++) {
            // layer 0: gather from y -> hc
            k_aggmm<<<GB, 1024, 0, stream>>>(y, hc, wpk, gcnb, lng, lnb, offs, esrc, enrm);
            // layer 1: gather from hc -> hn; gate blends into hc
            k_aggmm<<<GB, 1024, 0, stream>>>(hc, hn, wpk + 64 * DH, gcnb + DH, lng + DH, lnb + DH,
                                             offs, esrc, enrm);
            k_gate<false><<<GB, 1024, 0, stream>>>(hc, hn, gwpk, gateb, hc, nullptr, nullptr,
                                                   nullptr, nullptr, 0);
            // layer 2: gather from hc -> hn; gate + tanh + residual + RK4
            k_aggmm<<<GB, 1024, 0, stream>>>(hc, hn, wpk + 2 * 64 * DH, gcnb + 2 * DH,
                                             lng + 2 * DH, lnb + 2 * DH, offs, esrc, enrm);
            k_gate<true><<<GB, 1024, 0, stream>>>(hc, hn, gwpk, gateb, nullptr, y, hh, acc, sc, j);
        }
    }

    k_outproj<<<GB, 1024, 0, stream>>>(hh, wopk, bo, loutg, loutb, oacc);
    k_final<<<1, 128, 0, stream>>>(oacc, (float*)d_out);
}

// Round 2
// 10036.906 us; speedup vs baseline: 15.5394x; 15.5394x over previous
//
#include <hip/hip_runtime.h>

typedef unsigned int u32;
using bf16x8 = __attribute__((ext_vector_type(8))) short;
using f32x4  = __attribute__((ext_vector_type(4))) float;

#define NN 20000
#define EE 320000
#define DH 128
#define DIN 64
#define TSTEPS 20
#define LNEPS 1e-5f
#define NCHUNK 1250   // 20000 / 16-node wave chunks

// ---------- helpers ----------
__device__ __forceinline__ u32 f2bf(float f) {
    u32 x = __float_as_uint(f);
    return (x + 0x7fffu + ((x >> 16) & 1u)) >> 16;   // RNE to bf16 bits
}
__device__ __forceinline__ float bflo(u32 p) { return __uint_as_float(p << 16); }
__device__ __forceinline__ float bfhi(u32 p) { return __uint_as_float(p & 0xffff0000u); }
__device__ __forceinline__ u32 packbf(float a, float b) { return f2bf(a) | (f2bf(b) << 16); }
__device__ __forceinline__ float wredsum(float v) {
#pragma unroll
    for (int m = 32; m >= 1; m >>= 1) v += __shfl_xor(v, m, 64);
    return v;
}
__device__ __forceinline__ float sigm(float x) { return 1.f / (1.f + __expf(-x)); }
__device__ __forceinline__ void accum8(float* a, uint4 p, float w) {
    a[0] += w * bflo(p.x); a[1] += w * bfhi(p.x);
    a[2] += w * bflo(p.y); a[3] += w * bfhi(p.y);
    a[4] += w * bflo(p.z); a[5] += w * bfhi(p.z);
    a[6] += w * bflo(p.w); a[7] += w * bfhi(p.w);
}

// ---------- setup kernels (unchanged from round 1, known-good) ----------
__global__ void k_init(int* deg, float* oacc) {
    int i = blockIdx.x * blockDim.x + threadIdx.x;
    if (i < NN) deg[i] = 0;
    if (i < DH) oacc[i] = 0.f;
}

__global__ void k_scalars(const float* meth, const float* hist, const float* logd,
                          const float* resw, float* sc) {
    float msum = 0.f;
    for (int j = 0; j < DH; j++) msum += sigm(meth[j]);
    float msil = msum * (1.f / DH);
    float h0 = sigm(hist[0]), h1 = sigm(hist[1]), h2 = sigm(hist[2]), h3 = sigm(hist[3]);
    float act = 0.5f * (h0 + h2), rep = 0.5f * (h1 + h3);
    float access = fminf(fmaxf(act - rep + 0.5f, 0.f), 1.f);
    sc[0] = access * (1.f - msil);
    float depth = fminf(fmaxf(__expf(logd[0]), 0.1f), 3.f);
    sc[1] = depth / (float)(TSTEPS - 1);
    sc[2] = resw[0];
}

__global__ void k_deg(const int* col, int* deg) {
    int e = blockIdx.x * blockDim.x + threadIdx.x;
    if (e < EE) atomicAdd(&deg[col[e]], 1);
}

__global__ __launch_bounds__(1024) void k_scan(const int* deg, int* offs, int* cursor, float* dis) {
    __shared__ int part[1024];
    const int CH = (NN + 1023) / 1024;
    int t = threadIdx.x;
    int base = t * CH;
    int s = 0;
    for (int k = 0; k < CH; k++) { int i = base + k; if (i < NN) s += deg[i]; }
    part[t] = s;
    __syncthreads();
    for (int off = 1; off < 1024; off <<= 1) {
        int v = part[t];
        int add = (t >= off) ? part[t - off] : 0;
        __syncthreads();
        part[t] = v + add;
        __syncthreads();
    }
    int run = part[t] - s;
    for (int k = 0; k < CH; k++) {
        int i = base + k;
        if (i < NN) {
            offs[i] = run; cursor[i] = run;
            int d = deg[i];
            run += d;
            dis[i] = (d > 0) ? rsqrtf((float)d) : 0.f;
        }
    }
    if (t == 1023) offs[NN] = run;
}

__global__ void k_scatter(const int* row, const int* col, int* cursor, const float* dis,
                          int* esrc, float* enrm) {
    int e = blockIdx.x * blockDim.x + threadIdx.x;
    if (e < EE) {
        int c = col[e], r = row[e];
        int pos = atomicAdd(&cursor[c], 1);
        esrc[pos] = r;
        enrm[pos] = dis[r] * dis[c];
    }
}

// ---------- fragment-order weight packing ----------
// wfrag[l][q][j][lane][4xu32]: element i (0..7) = W_l[32q + 8*(lane>>4) + i][16j + (lane&15)]
// gfrag[q][j][lane][4xu32]:   same with gate_w (256x128), q=0..7
// wopk: round-1 pair-packed Wo for k_outproj
__global__ void k_pack(const float* gcnw, const float* gatew, const float* Wo,
                       u32* wfrag, u32* gfrag, u32* wopk) {
    int tid = blockIdx.x * blockDim.x + threadIdx.x;
    if (tid < 6144) {                       // 3 layers * 4q * 8j * 64 lanes
        int lane = tid & 63, rem = tid >> 6;
        int j = rem & 7; rem >>= 3;
        int q = rem & 3; int l = rem >> 2;
        const float* W = gcnw + l * DH * DH;
        int r0 = 32 * q + 8 * (lane >> 4);
        int c  = 16 * j + (lane & 15);
        u32* o = wfrag + tid * 4;
#pragma unroll
        for (int p = 0; p < 4; p++)
            o[p] = packbf(W[(r0 + 2 * p) * DH + c], W[(r0 + 2 * p + 1) * DH + c]);
    } else if (tid < 6144 + 4096) {         // 8q * 8j * 64 lanes
        int t = tid - 6144;
        int lane = t & 63, rem = t >> 6;
        int j = rem & 7, q = rem >> 3;
        int r0 = 32 * q + 8 * (lane >> 4);
        int c  = 16 * j + (lane & 15);
        u32* o = gfrag + t * 4;
#pragma unroll
        for (int p = 0; p < 4; p++)
            o[p] = packbf(gatew[(r0 + 2 * p) * DH + c], gatew[(r0 + 2 * p + 1) * DH + c]);
    } else if (tid < 6144 + 4096 + 8192) {  // 64*128 u32
        int t = tid - 10240;
        int k2 = t / DH, j = t % DH;
        wopk[t] = packbf(Wo[(2 * k2) * DH + j], Wo[(2 * k2 + 1) * DH + j]);
    }
}

// ---------- input projection (round-1, known-good) ----------
__global__ __launch_bounds__(1024) void k_inproj(const float* x, const float* Wi, const float* bi,
                                                 const float* g, const float* b, const float* sc,
                                                 u32* y, float* hh) {
    __shared__ float Wl[DIN * DH];
    for (int i = threadIdx.x; i < DIN * DH; i += 1024) Wl[i] = Wi[i];
    __syncthreads();
    int wv = threadIdx.x >> 6, t = threadIdx.x & 63;
    int n = blockIdx.x * 16 + wv;
    if (n >= NN) return;
    float xv = x[n * DIN + t];
    float2 bb = *(const float2*)&bi[2 * t];
    float y0 = bb.x, y1 = bb.y;
#pragma unroll
    for (int k = 0; k < DIN; k++) {
        float a = __shfl(xv, k, 64);
        float2 w = *(const float2*)&Wl[k * DH + 2 * t];
        y0 += a * w.x; y1 += a * w.y;
    }
    float mu = wredsum(y0 + y1) * (1.f / DH);
    float d0 = y0 - mu, d1 = y1 - mu;
    float var = wredsum(d0 * d0 + d1 * d1) * (1.f / DH);
    float r = rsqrtf(var + LNEPS);
    float2 gg = *(const float2*)&g[2 * t], lb = *(const float2*)&b[2 * t];
    float scale = sc[0];
    float v0 = fmaxf(d0 * r * gg.x + lb.x, 0.f) * scale;
    float v1 = fmaxf(d1 * r * gg.y + lb.y, 0.f) * scale;
    y[n * 64 + t] = packbf(v0, v1);
    *(float2*)&hh[n * DH + 2 * t] = make_float2(v0, v1);
}

// ---------- MFMA gather + GEMM + LN ----------
// wave = 16 nodes. Gather via 4 parallel quarter-wave chains; LDS tile stride 68 u32.
__global__ __launch_bounds__(256) void k_aggmm(const u32* __restrict__ src, u32* __restrict__ dst,
                                               const u32* __restrict__ wfrag,
                                               const float* __restrict__ bias,
                                               const float* __restrict__ lng,
                                               const float* __restrict__ lnb,
                                               const int* __restrict__ offs,
                                               const int* __restrict__ esrc,
                                               const float* __restrict__ enrm) {
    __shared__ u32 tile[4][16 * 68];
    int wv = threadIdx.x >> 6, lane = threadIdx.x & 63;
    int w = blockIdx.x * 4 + wv;
    if (w >= NCHUNK) return;
    int base = w * 16;
    int t4 = lane >> 4, sub = lane & 15;
    u32* my = tile[wv];

    // per-lane LN constants (col = 16j + sub in MFMA phase)
    float bb[8], gg[8], be[8];
#pragma unroll
    for (int j = 0; j < 8; j++) {
        bb[j] = bias[16 * j + sub];
        gg[j] = lng[16 * j + sub];
        be[j] = lnb[16 * j + sub];
    }
    int offv = offs[base + (lane < 17 ? lane : 16)];

    // gather: quarter t4 handles rows 4*t4+i; lane covers cols [8*sub, 8*sub+8)
    for (int i = 0; i < 4; i++) {
        int rrow = 4 * t4 + i;
        int e0 = __shfl(offv, rrow, 64);
        int e1 = __shfl(offv, rrow + 1, 64);
        float a[8] = {0.f, 0.f, 0.f, 0.f, 0.f, 0.f, 0.f, 0.f};
        int qb = t4 * 16;
        for (int eb = e0; eb < e1; eb += 16) {
            int cc = min(16, e1 - eb);
            int s = 0; float wgt = 0.f;
            if (sub < cc) { s = esrc[eb + sub]; wgt = enrm[eb + sub]; }
            int k = 0;
            for (; k + 4 <= cc; k += 4) {
                int s0 = __shfl(s, qb + k, 64),     s1 = __shfl(s, qb + k + 1, 64);
                int s2 = __shfl(s, qb + k + 2, 64), s3 = __shfl(s, qb + k + 3, 64);
                float w0 = __shfl(wgt, qb + k, 64),     w1 = __shfl(wgt, qb + k + 1, 64);
                float w2 = __shfl(wgt, qb + k + 2, 64), w3 = __shfl(wgt, qb + k + 3, 64);
                uint4 p0 = *(const uint4*)(src + s0 * 64 + sub * 4);
                uint4 p1 = *(const uint4*)(src + s1 * 64 + sub * 4);
                uint4 p2 = *(const uint4*)(src + s2 * 64 + sub * 4);
                uint4 p3 = *(const uint4*)(src + s3 * 64 + sub * 4);
                accum8(a, p0, w0); accum8(a, p1, w1); accum8(a, p2, w2); accum8(a, p3, w3);
            }
            for (; k < cc; k++) {
                int s0 = __shfl(s, qb + k, 64);
                float w0 = __shfl(wgt, qb + k, 64);
                uint4 p0 = *(const uint4*)(src + s0 * 64 + sub * 4);
                accum8(a, p0, w0);
            }
        }
        uint4 v;
        v.x = packbf(a[0], a[1]); v.y = packbf(a[2], a[3]);
        v.z = packbf(a[4], a[5]); v.w = packbf(a[6], a[7]);
        *(uint4*)(my + rrow * 68 + sub * 4) = v;
    }

    // MFMA: D[16 nodes][128] = A(tile) @ W, B-frags streamed from global (L2-hot)
    f32x4 acc[8];
#pragma unroll
    for (int j = 0; j < 8; j++) acc[j] = (f32x4){0.f, 0.f, 0.f, 0.f};
#pragma unroll
    for (int q = 0; q < 4; q++) {
        bf16x8 A = *(const bf16x8*)(my + (lane & 15) * 68 + q * 16 + t4 * 4);
#pragma unroll
        for (int j = 0; j < 8; j++) {
            bf16x8 B = *(const bf16x8*)(wfrag + ((q * 8 + j) * 64 + lane) * 4);
            acc[j] = __builtin_amdgcn_mfma_f32_16x16x32_bf16(A, B, acc[j], 0, 0, 0);
        }
    }

    // LN epilogue in C/D layout: node = base + 4*t4 + r, col = 16j + sub
    float s1[4] = {0.f, 0.f, 0.f, 0.f}, s2[4] = {0.f, 0.f, 0.f, 0.f};
#pragma unroll
    for (int j = 0; j < 8; j++)
#pragma unroll
        for (int r = 0; r < 4; r++) {
            float v = acc[j][r] + bb[j];
            acc[j][r] = v;
            s1[r] += v; s2[r] += v * v;
        }
    float mu[4], rs[4];
#pragma unroll
    for (int r = 0; r < 4; r++) {
#pragma unroll
        for (int m = 1; m <= 8; m <<= 1) {
            s1[r] += __shfl_xor(s1[r], m, 64);
            s2[r] += __shfl_xor(s2[r], m, 64);
        }
        mu[r] = s1[r] * (1.f / DH);
        float var = s2[r] * (1.f / DH) - mu[r] * mu[r];
        rs[r] = rsqrtf(var + LNEPS);
    }
#pragma unroll
    for (int j = 0; j < 8; j++)
#pragma unroll
        for (int r = 0; r < 4; r++) {
            float o = (acc[j][r] - mu[r]) * rs[r] * gg[j] + be[j];
            float po = __shfl_xor(o, 1, 64);
            if (!(sub & 1)) {
                int node = base + 4 * t4 + r;
                dst[node * 64 + j * 8 + (sub >> 1)] = packbf(o, po);
            }
        }
}

// ---------- MFMA gate (+ RK4 epilogue) ----------
// K=256 GEMM: A-frags straight from global hc/hn rows (A-layout). NOTE: hc/hcout alias
// when !LAST -> no __restrict__ on them.
template <bool LAST>
__global__ __launch_bounds__(256) void k_gate(const u32* hc, const u32* __restrict__ hn,
                                              const u32* __restrict__ gfrag,
                                              const float* __restrict__ gateb,
                                              u32* hcout, u32* ybuf,
                                              float* __restrict__ hh, float* __restrict__ acc_g,
                                              const float* __restrict__ sc, int rkj) {
    int wv = threadIdx.x >> 6, lane = threadIdx.x & 63;
    int w = blockIdx.x * 4 + wv;
    if (w >= NCHUNK) return;
    int base = w * 16;
    int t4 = lane >> 4, n = lane & 15;
    float gb[8];
#pragma unroll
    for (int j = 0; j < 8; j++) gb[j] = gateb[16 * j + n];

    bf16x8 A[8];
#pragma unroll
    for (int q = 0; q < 8; q++) {
        const u32* sp = (q < 4) ? hc : hn;
        int qq = q & 3;
        A[q] = *(const bf16x8*)(sp + (base + n) * 64 + qq * 16 + t4 * 4);
    }
    f32x4 acc[8];
#pragma unroll
    for (int j = 0; j < 8; j++) acc[j] = (f32x4){0.f, 0.f, 0.f, 0.f};
#pragma unroll
    for (int q = 0; q < 8; q++)
#pragma unroll
        for (int j = 0; j < 8; j++) {
            bf16x8 B = *(const bf16x8*)(gfrag + ((q * 8 + j) * 64 + lane) * 4);
            acc[j] = __builtin_amdgcn_mfma_f32_16x16x32_bf16(A[q], B, acc[j], 0, 0, 0);
        }

    float dt = 0.f, rw = 0.f;
    if (LAST) { dt = sc[1]; rw = sc[2]; }
#pragma unroll
    for (int j = 0; j < 8; j++)
#pragma unroll
        for (int r = 0; r < 4; r++) {
            int node = base + 4 * t4 + r;
            int ui = node * 64 + j * 8 + (n >> 1);
            float g = sigm(acc[j][r] + gb[j]);
            u32 ph = hn[ui], pc = hc[ui];
            float hnv = (n & 1) ? bfhi(ph) : bflo(ph);
            float hcv = (n & 1) ? bfhi(pc) : bflo(pc);
            float o = g * hnv + (1.f - g) * hcv;
            if (!LAST) {
                float po = __shfl_xor(o, 1, 64);
                if (!(n & 1)) hcout[ui] = packbf(o, po);
            } else {
                float z = fminf(fmaxf(o, -15.f), 15.f);
                float e = __expf(2.f * z);
                float th = (e - 1.f) / (e + 1.f);
                u32 py = ybuf[ui];
                float yv = (n & 1) ? bfhi(py) : bflo(py);
                float kk = th + rw * yv;
                float wj = dt * (1.f / 6.f) * ((rkj == 1 || rkj == 2) ? 2.f : 1.f);
                int fi = node * DH + 16 * j + n;
                float av = wj * kk;
                if (rkj != 0) av += acc_g[fi];
                acc_g[fi] = av;
                float hv = hh[fi];
                if (rkj < 3) {
                    float c = (rkj == 2) ? dt : 0.5f * dt;
                    float yo = hv + c * kk;
                    float pyo = __shfl_xor(yo, 1, 64);
                    if (!(n & 1)) ybuf[ui] = packbf(yo, pyo);
                } else {
                    float f = hv + av;
                    hh[fi] = f;
                    float pf = __shfl_xor(f, 1, 64);
                    if (!(n & 1)) ybuf[ui] = packbf(f, pf);
                }
            }
        }
}

// ---------- output projection + LN + global mean (round-1, known-good) ----------
__global__ __launch_bounds__(1024) void k_outproj(const float* __restrict__ hh, const u32* wopk,
                                                  const float* bo, const float* g, const float* b,
                                                  float* oacc) {
    __shared__ u32 Wl[64 * DH];
    __shared__ float red[DH];
    for (int i = threadIdx.x; i < 64 * DH; i += 1024) Wl[i] = wopk[i];
    if (threadIdx.x < DH) red[threadIdx.x] = 0.f;
    __syncthreads();
    int wv = threadIdx.x >> 6, t = threadIdx.x & 63;
    int n = blockIdx.x * 16 + wv;
    if (n < NN) {
        float2 hv = *(const float2*)&hh[n * DH + 2 * t];
        float h0 = hv.x, h1 = hv.y;
        float2 bb = *(const float2*)&bo[2 * t];
        float y0 = bb.x, y1 = bb.y;
#pragma unroll
        for (int k2 = 0; k2 < 64; k2++) {
            float a0 = __shfl(h0, k2, 64), a1 = __shfl(h1, k2, 64);
            uint2 wq = *(const uint2*)&Wl[k2 * DH + 2 * t];
            y0 += a0 * bflo(wq.x) + a1 * bfhi(wq.x);
            y1 += a0 * bflo(wq.y) + a1 * bfhi(wq.y);
        }
        float mu = wredsum(y0 + y1) * (1.f / DH);
        float d0 = y0 - mu, d1 = y1 - mu;
        float var = wredsum(d0 * d0 + d1 * d1) * (1.f / DH);
        float r = rsqrtf(var + LNEPS);
        float2 gg = *(const float2*)&g[2 * t], lb = *(const float2*)&b[2 * t];
        atomicAdd(&red[2 * t], d0 * r * gg.x + lb.x);
        atomicAdd(&red[2 * t + 1], d1 * r * gg.y + lb.y);
    }
    __syncthreads();
    if (threadIdx.x < DH) atomicAdd(&oacc[threadIdx.x], red[threadIdx.x]);
}

__global__ void k_final(const float* oacc, float* out) {
    int t = threadIdx.x;
    if (t < DH) out[t] = oacc[t] * (1.f / (float)NN);
}

// ---------- host ----------
extern "C" void kernel_launch(void* const* d_in, const int* in_sizes, int n_in,
                              void* d_out, int out_size, void* d_ws, size_t ws_size,
                              hipStream_t stream) {
    const float* x     = (const float*)d_in[0];
    const int*   ei    = (const int*)d_in[1];
    const float* Wi    = (const float*)d_in[2];
    const float* bi    = (const float*)d_in[3];
    const float* ling  = (const float*)d_in[4];
    const float* linb  = (const float*)d_in[5];
    const float* meth  = (const float*)d_in[6];
    const float* hist  = (const float*)d_in[7];
    const float* gcnw  = (const float*)d_in[8];
    const float* gcnb  = (const float*)d_in[9];
    const float* lng   = (const float*)d_in[10];
    const float* lnb   = (const float*)d_in[11];
    const float* gatew = (const float*)d_in[12];
    const float* gateb = (const float*)d_in[13];
    const float* resw  = (const float*)d_in[14];
    const float* logd  = (const float*)d_in[15];
    const float* Wo    = (const float*)d_in[16];
    const float* bo    = (const float*)d_in[17];
    const float* loutg = (const float*)d_in[18];
    const float* loutb = (const float*)d_in[19];

    char* wsb = (char*)d_ws;
    size_t off = 0;
    auto alloc = [&](size_t bytes) -> void* {
        void* p = wsb + off;
        off += (bytes + 255) & ~(size_t)255;
        return p;
    };
    float* sc     = (float*)alloc(32);
    int*   deg    = (int*)alloc(NN * 4);
    int*   offs   = (int*)alloc((NN + 1) * 4);
    int*   cursor = (int*)alloc(NN * 4);
    float* dis    = (float*)alloc(NN * 4);
    int*   esrc   = (int*)alloc(EE * 4);
    float* enrm   = (float*)alloc(EE * 4);
    u32*   wfrag  = (u32*)alloc(3 * 32 * 64 * 4 * 4);   // 3 layers * 32 frags * 64 lanes * 4 u32
    u32*   gfrag  = (u32*)alloc(64 * 64 * 4 * 4);       // 64 frags * 64 lanes * 4 u32
    u32*   wopk   = (u32*)alloc(64 * DH * 4);
    u32*   y      = (u32*)alloc((size_t)NN * 64 * 4);
    u32*   hc     = (u32*)alloc((size_t)NN * 64 * 4);
    u32*   hn     = (u32*)alloc((size_t)NN * 64 * 4);
    float* hh     = (float*)alloc((size_t)NN * DH * 4);
    float* acc    = (float*)alloc((size_t)NN * DH * 4);
    float* oacc   = (float*)alloc(DH * 4);

    const int* row = ei;
    const int* col = ei + EE;

    k_init<<<(NN + 255) / 256, 256, 0, stream>>>(deg, oacc);
    k_scalars<<<1, 1, 0, stream>>>(meth, hist, logd, resw, sc);
    k_deg<<<(EE + 255) / 256, 256, 0, stream>>>(col, deg);
    k_scan<<<1, 1024, 0, stream>>>(deg, offs, cursor, dis);
    k_scatter<<<(EE + 255) / 256, 256, 0, stream>>>(row, col, cursor, dis, esrc, enrm);
    k_pack<<<(6144 + 4096 + 8192 + 255) / 256, 256, 0, stream>>>(gcnw, gatew, Wo, wfrag, gfrag, wopk);

    const int GB1 = (NN + 15) / 16;       // 1250 blocks x 1024 thr (inproj/outproj)
    const int GB2 = (NCHUNK + 3) / 4;     // 313 blocks x 256 thr (4 waves = 4 chunks)

    k_inproj<<<GB1, 1024, 0, stream>>>(x, Wi, bi, ling, linb, sc, y, hh);

    const int LSZ = 32 * 64 * 4;          // u32 per layer of wfrag
    for (int s = 0; s < TSTEPS - 1; s++) {
        for (int j = 0; j < 4; j++) {
            k_aggmm<<<GB2, 256, 0, stream>>>(y, hc, wfrag, gcnb, lng, lnb, offs, esrc, enrm);
            k_aggmm<<<GB2, 256, 0, stream>>>(hc, hn, wfrag + LSZ, gcnb + DH, lng + DH, lnb + DH,
                                             offs, esrc, enrm);
            k_gate<false><<<GB2, 256, 0, stream>>>(hc, hn, gfrag, gateb, hc, y, hh, acc, sc, j);
            k_aggmm<<<GB2, 256, 0, stream>>>(hc, hn, wfrag + 2 * LSZ, gcnb + 2 * DH,
                                             lng + 2 * DH, lnb + 2 * DH, offs, esrc, enrm);
            k_gate<true><<<GB2, 256, 0, stream>>>(hc, hn, gfrag, gateb, hc, y, hh, acc, sc, j);
        }
    }

    k_outproj<<<GB1, 1024, 0, stream>>>(hh, wopk, bo, loutg, loutb, oacc);
    k_final<<<1, 128, 0, stream>>>(oacc, (float*)d_out);
}